// Round 8
// baseline (1848.824 us; speedup 1.0000x reference)
//
#include <hip/hip_runtime.h>
#include <cstdint>
#include <cstddef>

#define S_LEN 1024
#define DM 512
#define NHEAD 8
#define HDIM 64
#define NLAYER 4
#define FFD 2048
#define VOC 32000
#define WINSZ 128
#define GLOBSZ 16

using half8 = __attribute__((ext_vector_type(8))) _Float16;
using f32x4 = __attribute__((ext_vector_type(4))) float;

static __device__ __forceinline__ f32x4 mfma16(half8 a, half8 b, f32x4 c) {
  return __builtin_amdgcn_mfma_f32_16x16x32_f16(a, b, c, 0, 0, 0);
}

typedef __attribute__((address_space(1))) const void gvoid;
typedef __attribute__((address_space(3))) void lvoid;
static __device__ __forceinline__ void gload16(const void* g, void* l) {
  __builtin_amdgcn_global_load_lds((gvoid*)g, (lvoid*)l, 16, 0, 0);
}
template <int N>
static __device__ __forceinline__ void waitv() {
  asm volatile("s_waitcnt vmcnt(%0)" :: "i"(N) : "memory");
}

// ---------- batched transpose + cast: picks (inA,outA) for z<splitZ else (inB,outB)
__global__ __launch_bounds__(256) void transpose2_k(const float* __restrict__ inA,
                                                    const float* __restrict__ inB,
                                                    _Float16* __restrict__ outA,
                                                    _Float16* __restrict__ outB,
                                                    int R, int C, int splitZ)
{
  __shared__ float t[32][33];
  int z = blockIdx.z;
  const float* ip;
  _Float16* op;
  if (z < splitZ) { ip = inA + (size_t)z * R * C; op = outA + (size_t)z * R * C; }
  else { ip = inB + (size_t)(z - splitZ) * R * C; op = outB + (size_t)(z - splitZ) * R * C; }
  int c0 = blockIdx.x * 32, r0 = blockIdx.y * 32;
  int tx = threadIdx.x & 31, ty = threadIdx.x >> 5;
#pragma unroll
  for (int i = 0; i < 32; i += 8)
    t[ty + i][tx] = ip[(size_t)(r0 + ty + i) * C + c0 + tx];
  __syncthreads();
#pragma unroll
  for (int i = 0; i < 32; i += 8)
    op[(size_t)(c0 + ty + i) * R + r0 + tx] = (_Float16)t[tx][ty + i];
}

// ---------- dual embedding gather * sqrt(D) (LN now fused into the consuming GEMM)
__global__ __launch_bounds__(256) void embed2_k(const int* __restrict__ src,
                                                const int* __restrict__ tgt,
                                                const float* __restrict__ enc_embed,
                                                const float* __restrict__ dec_embed,
                                                float* __restrict__ xbuf,
                                                float* __restrict__ ybuf)
{
  int which = blockIdx.y;
  const int* ids = which ? tgt : src;
  const float* emb = which ? dec_embed : enc_embed;
  float* xout = which ? ybuf : xbuf;

  int row = blockIdx.x * 4 + (threadIdx.x >> 6);
  int lane = threadIdx.x & 63;
  const float* er = emb + (size_t)ids[row] * DM + lane * 8;
  float4 v0 = *(const float4*)er;
  float4 v1 = *(const float4*)(er + 4);
  float* xr = xout + (size_t)row * DM + lane * 8;
  const float sc = 22.627416997969522f;
  xr[0] = v0.x * sc; xr[1] = v0.y * sc; xr[2] = v0.z * sc; xr[3] = v0.w * sc;
  xr[4] = v1.x * sc; xr[5] = v1.y * sc; xr[6] = v1.z * sc; xr[7] = v1.w * sc;
}

// ---------- LayerNorm fp32 -> fp16 (final decoder LN only)
__global__ __launch_bounds__(256) void ln_k(const float* __restrict__ x,
                                            const float* __restrict__ gamma,
                                            const float* __restrict__ beta,
                                            _Float16* __restrict__ outp)
{
  int row = blockIdx.x * 4 + (threadIdx.x >> 6);
  int lane = threadIdx.x & 63;
  const float* xr = x + (size_t)row * DM + lane * 8;
  float4 v0 = *(const float4*)xr;
  float4 v1 = *(const float4*)(xr + 4);
  float vals[8] = {v0.x, v0.y, v0.z, v0.w, v1.x, v1.y, v1.z, v1.w};
  float s = 0.f, ss = 0.f;
#pragma unroll
  for (int j = 0; j < 8; ++j) { s += vals[j]; ss += vals[j] * vals[j]; }
#pragma unroll
  for (int m = 1; m < 64; m <<= 1) { s += __shfl_xor(s, m); ss += __shfl_xor(ss, m); }
  float mean = s * (1.f / 512.f);
  float var = ss * (1.f / 512.f) - mean * mean;
  float rstd = rsqrtf(var + 1e-5f);
  _Float16* orow = outp + (size_t)row * DM + lane * 8;
  const float* gp = gamma + lane * 8;
  const float* bp = beta + lane * 8;
#pragma unroll
  for (int j = 0; j < 8; ++j)
    orow[j] = (_Float16)(gp[j] * (vals[j] - mean) * rstd + bp[j]);
}

// ======================================================================
// Fused LayerNorm + GEMM: C[M,N] = LN(A_f32)[M,512](->f16) * B^T[N,512] + bias
// A-tile (64 rows x full K=512) normalized into resident LDS once; only B staged.
// EPI: 0 bias->f16 ; 1 bias+gelu->f16
// MODE: 0 plain ; 1 self-QKV (rope Q/K, V->V^T) ; 2 batched cross-KV ; 3 rope all (cross-Q)
// LDS = 64KB A + 2x8KB B = 80KB -> 2 blocks/CU. WIDE waves (16 rows x 64 cols).
template <int EPI, int MODE>
__global__ __launch_bounds__(256) void gemmln_k(const float* __restrict__ A,
                                                const _Float16* __restrict__ B,
                                                const float* __restrict__ gamma,
                                                const float* __restrict__ beta,
                                                const float* __restrict__ bias,
                                                void* __restrict__ Cout,
                                                _Float16* __restrict__ vtout,
                                                int N)
{
  constexpr int FNW = 4;
  __shared__ __align__(16) _Float16 As[64 * 512];
  __shared__ __align__(16) _Float16 Bs[2][64 * 64];
  const int tid = threadIdx.x;
  const int lane = tid & 63, wid = tid >> 6;
  const int g = lane >> 4, ql = lane & 15;
  const int bm = blockIdx.x * 64, bn = blockIdx.y * 64;

  const _Float16* Bp;
  if constexpr (MODE == 2) {
    int srcrow0 = ((bn >> 10) * 8 + 5 + ((bn >> 9) & 1)) * 512 + (bn & 511);
    Bp = B + (size_t)srcrow0 * 512;
  } else {
    Bp = B + (size_t)bn * 512;
  }

  auto stageB = [&](int buf, int kt) {
#pragma unroll
    for (int r2 = 0; r2 < 2; ++r2) {
      int off = r2 * 4096 + tid * 16;
      int row = off >> 7, slot = (off >> 4) & 7;
      gload16(Bp + (size_t)row * 512 + kt + ((slot ^ (row & 7)) << 3),
              (char*)&Bs[buf][0] + r2 * 4096 + wid * 1024);
    }
  };

  stageB(0, 0); // oldest in-flight; prologue's own waits drain it

  // ---- LN prologue: quad (4 lanes) per row, two-pass (stats, then normalize+write)
  {
    const int row = wid * 16 + (lane >> 2);
    const int chunk = lane & 3;
    const float* ap = A + (size_t)(bm + row) * 512 + chunk * 128;
    float s = 0.f, ss = 0.f;
#pragma unroll
    for (int j = 0; j < 32; ++j) {
      float4 v = *(const float4*)(ap + j * 4);
      s += v.x + v.y + v.z + v.w;
      ss += v.x * v.x + v.y * v.y + v.z * v.z + v.w * v.w;
    }
    s += __shfl_xor(s, 1); ss += __shfl_xor(ss, 1);
    s += __shfl_xor(s, 2); ss += __shfl_xor(ss, 2);
    const float mean = s * (1.f / 512.f);
    const float rstd = rsqrtf(ss * (1.f / 512.f) - mean * mean + 1e-5f);
    const float* gp = gamma + chunk * 128;
    const float* bp = beta + chunk * 128;
    auto nrm = [&](float a, float gg, float bb) {
      return (_Float16)(gg * (a - mean) * rstd + bb);
    };
#pragma unroll
    for (int j = 0; j < 16; ++j) {
      float4 a0 = *(const float4*)(ap + j * 8);
      float4 a1 = *(const float4*)(ap + j * 8 + 4);
      float4 g0 = *(const float4*)(gp + j * 8);
      float4 g1 = *(const float4*)(gp + j * 8 + 4);
      float4 b0 = *(const float4*)(bp + j * 8);
      float4 b1 = *(const float4*)(bp + j * 8 + 4);
      union { _Float16 h[8]; uint4 u; } pk;
      pk.h[0] = nrm(a0.x, g0.x, b0.x); pk.h[1] = nrm(a0.y, g0.y, b0.y);
      pk.h[2] = nrm(a0.z, g0.z, b0.z); pk.h[3] = nrm(a0.w, g0.w, b0.w);
      pk.h[4] = nrm(a1.x, g1.x, b1.x); pk.h[5] = nrm(a1.y, g1.y, b1.y);
      pk.h[6] = nrm(a1.z, g1.z, b1.z); pk.h[7] = nrm(a1.w, g1.w, b1.w);
      int slot16 = chunk * 16 + j;
      int seg = slot16 >> 3, sub = slot16 & 7;
      *(uint4*)((char*)As + row * 1024 + seg * 128 + ((sub ^ (row & 7)) << 4)) = pk.u;
    }
  }
  asm volatile("s_waitcnt lgkmcnt(0)" ::: "memory");

  f32x4 acc[FNW];
#pragma unroll
  for (int b = 0; b < FNW; ++b) acc[b] = f32x4{0.f, 0.f, 0.f, 0.f};

  const int arow = wid * 16 + ql;
  const int abyte_base = arow * 1024;

#pragma unroll
  for (int t = 0; t < 8; ++t) {
    __builtin_amdgcn_s_barrier();      // LN visible (t=0); compute(t-1) finished (t>0)
    if (t + 1 < 8) stageB((t + 1) & 1, (t + 1) << 6);
    if (t + 1 < 8) waitv<2>(); else waitv<0>();
    __builtin_amdgcn_sched_barrier(0);
    const int cur = t & 1;
#pragma unroll
    for (int kk = 0; kk < 2; ++kk) {
      half8 af = *(const half8*)((const char*)As + abyte_base + t * 128 +
                                 (((kk * 4 + g) ^ (arow & 7)) << 4));
      half8 bf[FNW];
#pragma unroll
      for (int b = 0; b < FNW; ++b) {
        int row = b * 16 + ql;
        bf[b] = *(const half8*)((const char*)&Bs[cur][0] + row * 128 +
                                (((kk * 4 + g) ^ (row & 7)) << 4));
      }
#pragma unroll
      for (int b = 0; b < FNW; ++b) acc[b] = mfma16(af, bf[b], acc[b]);
    }
  }

  // ---- epilogue (same wiring as gemm_k, FMW=1)
  const int row0 = bm + wid * 16 + g * 4;
  float v[FNW][4];
#pragma unroll
  for (int b2 = 0; b2 < FNW; ++b2) {
    int col = bn + b2 * 16 + ql;
    float bv;
    if constexpr (MODE == 2) {
      int bcol = ((col >> 10) * 8 + 5 + ((col >> 9) & 1)) * 512 + (col & 511);
      bv = bias[bcol];
    } else {
      bv = bias[col];
    }
#pragma unroll
    for (int r2 = 0; r2 < 4; ++r2) v[b2][r2] = acc[b2][r2] + bv;
  }
  if constexpr (MODE != 0) {
    const int seg = bn >> 9;
    bool dorope = (MODE == 3) || (MODE == 1 && seg < 2) ||
                  (MODE == 2 && ((bn >> 9) & 1) == 0);
    if (dorope) {
      const float scale = (MODE == 3 || (MODE == 1 && seg == 0)) ? 0.125f : 1.0f;
#pragma unroll
      for (int b2 = 0; b2 < 2; ++b2) {
        int d = b2 * 16 + ql;
        float inv = __expf(-(float)d * 0.28782313662425574f); // 10000^(-d/32)
#pragma unroll
        for (int r2 = 0; r2 < 4; ++r2) {
          float sp = (float)((row0 & 1023) + r2);
          float sn, cs; __sincosf(sp * inv, &sn, &cs);
          float x1 = v[b2][r2], x2 = v[b2 + 2][r2];
          v[b2][r2]     = (x1 * cs - x2 * sn) * scale;
          v[b2 + 2][r2] = (x1 * sn + x2 * cs) * scale;
        }
      }
    }
  }
#pragma unroll
  for (int b2 = 0; b2 < FNW; ++b2) {
    int col = bn + b2 * 16 + ql;
    if constexpr (MODE == 1) {
      if (col < 1024) {
#pragma unroll
        for (int r2 = 0; r2 < 4; ++r2)
          ((_Float16*)Cout)[(size_t)(row0 + r2) * 1024 + col] = (_Float16)v[b2][r2];
      } else {
        int rowidx = ((row0 >> 10) << 9) + (col - 1024);
        union { _Float16 h[4]; uint2 u; } pk;
#pragma unroll
        for (int r2 = 0; r2 < 4; ++r2) pk.h[r2] = (_Float16)v[b2][r2];
        *(uint2*)&vtout[((size_t)rowidx << 10) + (row0 & 1023)] = pk.u;
      }
    } else if constexpr (MODE == 2) {
      if ((col & 1023) < 512) {
#pragma unroll
        for (int r2 = 0; r2 < 4; ++r2)
          ((_Float16*)Cout)[(size_t)(row0 + r2) * 2048 + ((col >> 10) << 9) + (col & 511)] = (_Float16)v[b2][r2];
      } else {
        int rowidx = (col & ~1023) + ((row0 >> 10) << 9) + (col & 511);
        union { _Float16 h[4]; uint2 u; } pk;
#pragma unroll
        for (int r2 = 0; r2 < 4; ++r2) pk.h[r2] = (_Float16)v[b2][r2];
        *(uint2*)&vtout[((size_t)rowidx << 10) + (row0 & 1023)] = pk.u;
      }
    } else {
#pragma unroll
      for (int r2 = 0; r2 < 4; ++r2) {
        float x = v[b2][r2];
        if constexpr (EPI == 1) {
          float u = x;
          x = u / (1.f + __expf(-1.5957691216057308f * (u + 0.044715f * u * u * u)));
        }
        ((_Float16*)Cout)[(size_t)(row0 + r2) * N + col] = (_Float16)x;
      }
    }
  }
}

// ---------- GEMM (round-7 structure, f16 A): attn-out / FFN2 / cross-out / logits
template <int BM, int BN, int EPI, int MODE, bool SWZ = false, bool NT = false>
__global__ __launch_bounds__(256) void gemm_k(const _Float16* __restrict__ A,
                                              const _Float16* __restrict__ B,
                                              const float* __restrict__ bias,
                                              const float* __restrict__ resid,
                                              void* __restrict__ Cout,
                                              _Float16* __restrict__ vtout,
                                              int M, int N, int K)
{
  constexpr bool WIDE = (BN >= 64);
  constexpr int WAVE_M = WIDE ? BM / 4 : BM / 2;
  constexpr int WAVE_N = WIDE ? BN : BN / 2;
  constexpr int FMW = WAVE_M / 16;
  constexpr int FNW = WIDE ? BN / 16 : BN / 32;
  constexpr int LPS = BM / 32 + BN / 32;

  __shared__ __align__(16) _Float16 As[3][BM * 64];
  __shared__ __align__(16) _Float16 Bs[3][BN * 64];
  const int tid = threadIdx.x;
  const int lane = tid & 63, wid = tid >> 6;
  const int g = lane >> 4, ql = lane & 15;

  int bm, bn;
  if constexpr (SWZ) {
    const int gx = gridDim.x;
    const int nwg = gx * gridDim.y;
    const int orig = blockIdx.y * gx + blockIdx.x;
    const int q = nwg >> 3, r = nwg & 7;
    const int xcd = orig & 7, rest = orig >> 3;
    const int id = (xcd < r ? xcd * (q + 1) : r * (q + 1) + (xcd - r) * q) + rest;
    bm = (id % gx) * BM; bn = (id / gx) * BN;
  } else {
    bm = blockIdx.x * BM; bn = blockIdx.y * BN;
  }
  const int wm = WIDE ? wid * WAVE_M : (wid >> 1) * WAVE_M;
  const int wn = WIDE ? 0 : (wid & 1) * WAVE_N;

  const _Float16* Bp = B + (size_t)bn * K;

  f32x4 acc[FMW][FNW];
#pragma unroll
  for (int a = 0; a < FMW; ++a)
#pragma unroll
    for (int b = 0; b < FNW; ++b) acc[a][b] = f32x4{0.f, 0.f, 0.f, 0.f};

  auto stage = [&](int buf, int kt) {
#pragma unroll
    for (int r2 = 0; r2 < BM / 32; ++r2) {
      int off = r2 * 4096 + tid * 16;
      int row = off >> 7, slot = (off >> 4) & 7;
      gload16(A + (size_t)(bm + row) * K + kt + ((slot ^ (row & 7)) << 3),
              (char*)&As[buf][0] + r2 * 4096 + wid * 1024);
    }
#pragma unroll
    for (int r2 = 0; r2 < BN / 32; ++r2) {
      int off = r2 * 4096 + tid * 16;
      int row = off >> 7, slot = (off >> 4) & 7;
      gload16(Bp + (size_t)row * K + kt + ((slot ^ (row & 7)) << 3),
              (char*)&Bs[buf][0] + r2 * 4096 + wid * 1024);
    }
  };

  auto compute = [&](int cur) {
#pragma unroll
    for (int kk = 0; kk < 2; ++kk) {
      half8 af[FMW], bf[FNW];
#pragma unroll
      for (int a = 0; a < FMW; ++a) {
        int row = wm + a * 16 + ql;
        af[a] = *(const half8*)((const char*)&As[cur][0] + row * 128 + (((kk * 4 + g) ^ (row & 7)) << 4));
      }
#pragma unroll
      for (int b = 0; b < FNW; ++b) {
        int row = wn + b * 16 + ql;
        bf[b] = *(const half8*)((const char*)&Bs[cur][0] + row * 128 + (((kk * 4 + g) ^ (row & 7)) << 4));
      }
#pragma unroll
      for (int a = 0; a < FMW; ++a)
#pragma unroll
        for (int b = 0; b < FNW; ++b) acc[a][b] = mfma16(af[a], bf[b], acc[a][b]);
    }
  };

  const int nk = K >> 6;
  stage(0, 0);
  stage(1, 64);
  for (int t = 0; t < nk; ++t) {
    if (t + 1 < nk) waitv<LPS>(); else waitv<0>();
    __builtin_amdgcn_s_barrier();
    __builtin_amdgcn_sched_barrier(0);
    compute(t % 3);
    if (t + 2 < nk) stage((t + 2) % 3, (t + 2) << 6);
  }

#pragma unroll
  for (int a = 0; a < FMW; ++a) {
    const int row0 = bm + wm + a * 16 + g * 4;
#pragma unroll
    for (int b2 = 0; b2 < FNW; ++b2) {
      int col = bn + wn + b2 * 16 + ql;
      float bv = bias[col];
#pragma unroll
      for (int r2 = 0; r2 < 4; ++r2) {
        float x = acc[a][b2][r2] + bv;
        if constexpr (EPI == 1) {
          float u = x;
          x = u / (1.f + __expf(-1.5957691216057308f * (u + 0.044715f * u * u * u)));
        }
        if constexpr (EPI == 2) x += resid[(size_t)(row0 + r2) * N + col];
        if constexpr (EPI == 0 || EPI == 1)
          ((_Float16*)Cout)[(size_t)(row0 + r2) * N + col] = (_Float16)x;
        else if constexpr (NT)
          __builtin_nontemporal_store(x, &((float*)Cout)[(size_t)(row0 + r2) * N + col]);
        else
          ((float*)Cout)[(size_t)(row0 + r2) * N + col] = x;
      }
    }
  }
}

// ---------- banded flash attention; Q/K pre-roped (Q pre-scaled), V in V^T layout
template <bool CAUSAL>
__global__ __launch_bounds__(128) void attn_k(const _Float16* __restrict__ qb, int qs, int qoff,
                                              const _Float16* __restrict__ kb, int ks, int koff,
                                              const _Float16* __restrict__ vt,
                                              _Float16* __restrict__ out)
{
  __shared__ _Float16 plds[2][16 * 40];
  const int bh = blockIdx.y, b = bh >> 3, h = bh & 7;
  const int wid = threadIdx.x >> 6, lane = threadIdx.x & 63;
  const int g = lane >> 4, ql = lane & 15;
  const int q0 = blockIdx.x * 32 + wid * 16;
  const size_t rb = (size_t)b * S_LEN;

  half8 qf0, qf1;
  {
    const _Float16* qp = qb + (rb + q0 + ql) * qs + qoff + h * HDIM + g * 8;
    qf0 = *(const half8*)qp;
    qf1 = *(const half8*)(qp + 32);
  }
  float mrun[4] = {-1e30f, -1e30f, -1e30f, -1e30f};
  float srun[4] = {0.f, 0.f, 0.f, 0.f};
  f32x4 oacc[4];
#pragma unroll
  for (int c = 0; c < 4; ++c) oacc[c] = f32x4{0.f, 0.f, 0.f, 0.f};

  const _Float16* vbase = vt + (((size_t)(b * 512 + h * HDIM)) << 10);
  _Float16* pw = plds[wid];

  auto proc = [&](int k0) {
    const _Float16* kp = kb + (rb + k0 + ql) * ks + koff + h * HDIM + g * 8;
    half8 kf00 = *(const half8*)kp;
    half8 kf01 = *(const half8*)(kp + 32);
    half8 kf10 = *(const half8*)(kp + (size_t)16 * ks);
    half8 kf11 = *(const half8*)(kp + (size_t)16 * ks + 32);

    f32x4 s0 = f32x4{0.f, 0.f, 0.f, 0.f};
    f32x4 s1 = f32x4{0.f, 0.f, 0.f, 0.f};
    s0 = mfma16(qf0, kf00, s0); s0 = mfma16(qf1, kf01, s0);
    s1 = mfma16(qf0, kf10, s1); s1 = mfma16(qf1, kf11, s1);

    float p0[4], p1[4];
#pragma unroll
    for (int r = 0; r < 4; ++r) {
      int i = q0 + 4 * g + r;
      int j0 = k0 + ql, j1 = j0 + 16;
      float a0 = s0[r], a1 = s1[r];
      int d0 = i - j0, d1 = i - j1;
      bool ok0 = (d0 <= WINSZ && d0 >= -WINSZ) || (i < GLOBSZ) || (j0 < GLOBSZ);
      bool ok1 = (d1 <= WINSZ && d1 >= -WINSZ) || (i < GLOBSZ) || (j1 < GLOBSZ);
      if (CAUSAL) { ok0 = ok0 && (j0 <= i); ok1 = ok1 && (j1 <= i); }
      a0 = ok0 ? a0 : -1e9f;
      a1 = ok1 ? a1 : -1e9f;
      float mx = fmaxf(a0, a1);
      mx = fmaxf(mx, __shfl_xor(mx, 1));
      mx = fmaxf(mx, __shfl_xor(mx, 2));
      mx = fmaxf(mx, __shfl_xor(mx, 4));
      mx = fmaxf(mx, __shfl_xor(mx, 8));
      float mnew = fmaxf(mrun[r], mx);
      float alpha = __expf(mrun[r] - mnew);
      float e0 = __expf(a0 - mnew), e1 = __expf(a1 - mnew);
      float ps = e0 + e1;
      ps += __shfl_xor(ps, 1);
      ps += __shfl_xor(ps, 2);
      ps += __shfl_xor(ps, 4);
      ps += __shfl_xor(ps, 8);
      srun[r] = srun[r] * alpha + ps;
      mrun[r] = mnew;
#pragma unroll
      for (int c = 0; c < 4; ++c) oacc[c][r] *= alpha;
      p0[r] = e0; p1[r] = e1;
    }
#pragma unroll
    for (int r = 0; r < 4; ++r) {
      pw[(4 * g + r) * 40 + ql] = (_Float16)p0[r];
      pw[(4 * g + r) * 40 + 16 + ql] = (_Float16)p1[r];
    }
    half8 pa = *(const half8*)&pw[ql * 40 + g * 8];
#pragma unroll
    for (int c = 0; c < 4; ++c) {
      half8 vf = *(const half8*)(vbase + (((size_t)(16 * c + ql)) << 10) + k0 + 8 * g);
      oacc[c] = mfma16(pa, vf, oacc[c]);
    }
  };

  const int kend = CAUSAL ? (q0 + 16) : S_LEN;
  int lo = 0, hi = kend;
  if (q0 >= GLOBSZ) {
    lo = (q0 - WINSZ) & ~31;
    if (lo < 0) lo = 0;
    if (!CAUSAL) {
      int h2 = q0 + 16 + WINSZ;
      hi = (h2 < kend) ? h2 : kend;
    }
  }
  if (lo > 0) proc(0);
  for (int k0 = lo; k0 < hi; k0 += 32) proc(k0);

#pragma unroll
  for (int c = 0; c < 4; ++c)
#pragma unroll
    for (int r = 0; r < 4; ++r) {
      float val = oacc[c][r] / srun[r];
      out[(rb + q0 + 4 * g + r) * DM + h * HDIM + 16 * c + ql] = (_Float16)val;
    }
}

// =====================================================================
extern "C" void kernel_launch(void* const* d_in, const int* in_sizes, int n_in,
                              void* d_out, int out_size, void* d_ws, size_t ws_size,
                              hipStream_t stream)
{
  const int*   src         = (const int*)d_in[0];
  const int*   tgt         = (const int*)d_in[1];
  const float* enc_embed   = (const float*)d_in[2];
  const float* dec_embed   = (const float*)d_in[3];
  const float* enc_attn_w  = (const float*)d_in[4];
  const float* enc_attn_b  = (const float*)d_in[5];
  const float* enc_ln      = (const float*)d_in[6];
  const float* enc_ffn_w1  = (const float*)d_in[7];
  const float* enc_ffn_b1  = (const float*)d_in[8];
  const float* enc_ffn_w2  = (const float*)d_in[9];
  const float* enc_ffn_b2  = (const float*)d_in[10];
  const float* enc_fln     = (const float*)d_in[11];
  const float* dec_attn_w  = (const float*)d_in[12];
  const float* dec_attn_b  = (const float*)d_in[13];
  const float* dec_ln      = (const float*)d_in[14];
  const float* dec_ffn_w1  = (const float*)d_in[15];
  const float* dec_ffn_b1  = (const float*)d_in[16];
  const float* dec_ffn_w2  = (const float*)d_in[17];
  const float* dec_ffn_b2  = (const float*)d_in[18];
  const float* dec_fln     = (const float*)d_in[19];
  const float* out_w       = (const float*)d_in[20];
  const float* out_b       = (const float*)d_in[21];
  float* logits = (float*)d_out;

  char* wsp = (char*)d_ws;
  size_t off = 0;
  auto alloc = [&](size_t bytes) -> void* {
    void* p = wsp + off;
    off += (bytes + 255) & ~(size_t)255;
    return p;
  };
  _Float16* enc_attn_wt = (_Float16*)alloc((size_t)16 * 512 * 512 * 2);
  _Float16* dec_attn_wt = (_Float16*)alloc((size_t)32 * 512 * 512 * 2);
  _Float16* e_ffn1_wt   = (_Float16*)alloc((size_t)4 * 2048 * 512 * 2);
  _Float16* e_ffn2_wt   = (_Float16*)alloc((size_t)4 * 2048 * 512 * 2);
  _Float16* d_ffn1_wt   = (_Float16*)alloc((size_t)4 * 2048 * 512 * 2);
  _Float16* d_ffn2_wt   = (_Float16*)alloc((size_t)4 * 2048 * 512 * 2);
  _Float16* out_wt      = (_Float16*)alloc((size_t)VOC * 512 * 2);
  float*    xbuf        = (float*)alloc((size_t)2048 * 512 * 4);
  float*    ybuf        = (float*)alloc((size_t)2048 * 512 * 4);
  _Float16* nbuf        = (_Float16*)alloc((size_t)2048 * 512 * 2);
  _Float16* qkvb        = (_Float16*)alloc((size_t)2048 * 1024 * 2);
  _Float16* aob         = (_Float16*)alloc((size_t)2048 * 512 * 2);
  _Float16* hbuf        = (_Float16*)alloc((size_t)2048 * 2048 * 2);
  _Float16* cqb         = (_Float16*)alloc((size_t)2048 * 512 * 2);
  _Float16* ckvb        = (_Float16*)alloc((size_t)2048 * 2048 * 2);
  _Float16* vts         = (_Float16*)alloc((size_t)2 * 512 * 1024 * 2);
  _Float16* vtc         = (_Float16*)alloc((size_t)8 * 512 * 1024 * 2);

  // ---- weight prep (transpose + fp16 cast), batched
  transpose2_k<<<dim3(16, 16, 48), 256, 0, stream>>>(enc_attn_w, dec_attn_w,
                                                     enc_attn_wt, dec_attn_wt, 512, 512, 16);
  transpose2_k<<<dim3(64, 16, 8), 256, 0, stream>>>(enc_ffn_w1, dec_ffn_w1,
                                                    e_ffn1_wt, d_ffn1_wt, 512, 2048, 4);
  transpose2_k<<<dim3(16, 64, 8), 256, 0, stream>>>(enc_ffn_w2, dec_ffn_w2,
                                                    e_ffn2_wt, d_ffn2_wt, 2048, 512, 4);
  transpose2_k<<<dim3(1000, 16, 1), 256, 0, stream>>>(out_w, out_w, out_wt, out_wt, 512, VOC, 1);

  embed2_k<<<dim3(512, 2), 256, 0, stream>>>(src, tgt, enc_embed, dec_embed, xbuf, ybuf);

  // ---- encoder
  for (int l = 0; l < NLAYER; ++l) {
    const float* g0 = enc_ln + ((size_t)(l * 2 + 0) * 2 + 0) * 512;
    gemmln_k<0, 1><<<dim3(32, 24), 256, 0, stream>>>(
        xbuf, enc_attn_wt + (size_t)l * 4 * 262144, g0, g0 + 512,
        enc_attn_b + (size_t)l * 4 * 512, qkvb, vts, 1536);
    attn_k<false><<<dim3(32, 16), 128, 0, stream>>>(qkvb, 1024, 0, qkvb, 1024, 512, vts, aob);
    gemm_k<64, 32, 2, 0><<<dim3(32, 16), 256, 0, stream>>>(
        aob, enc_attn_wt + (size_t)(l * 4 + 3) * 262144,
        enc_attn_b + (size_t)(l * 4 + 3) * 512, xbuf, xbuf, nullptr, 2048, 512, 512);
    const float* g1 = enc_ln + ((size_t)(l * 2 + 1) * 2 + 0) * 512;
    gemmln_k<1, 0><<<dim3(32, 32), 256, 0, stream>>>(
        xbuf, e_ffn1_wt + (size_t)l * 2048 * 512, g1, g1 + 512,
        enc_ffn_b1 + (size_t)l * 2048, hbuf, nullptr, 2048);
    gemm_k<64, 32, 2, 0><<<dim3(32, 16), 256, 0, stream>>>(
        hbuf, e_ffn2_wt + (size_t)l * 512 * 2048,
        enc_ffn_b2 + (size_t)l * 512, xbuf, xbuf, nullptr, 2048, 512, 2048);
  }

  // ---- all 4 decoder layers' cross K/V projections in one fused-LN GEMM
  gemmln_k<0, 2><<<dim3(32, 64), 256, 0, stream>>>(
      xbuf, dec_attn_wt, enc_fln, enc_fln + 512, dec_attn_b, ckvb, vtc, 4096);

  // ---- decoder
  for (int l = 0; l < NLAYER; ++l) {
    const float* g0 = dec_ln + ((size_t)(l * 3 + 0) * 2 + 0) * 512;
    gemmln_k<0, 1><<<dim3(32, 24), 256, 0, stream>>>(
        ybuf, dec_attn_wt + (size_t)l * 8 * 262144, g0, g0 + 512,
        dec_attn_b + (size_t)l * 8 * 512, qkvb, vts, 1536);
    attn_k<true><<<dim3(32, 16), 128, 0, stream>>>(qkvb, 1024, 0, qkvb, 1024, 512, vts, aob);
    gemm_k<64, 32, 2, 0><<<dim3(32, 16), 256, 0, stream>>>(
        aob, dec_attn_wt + (size_t)(l * 8 + 3) * 262144,
        dec_attn_b + (size_t)(l * 8 + 3) * 512, ybuf, ybuf, nullptr, 2048, 512, 512);
    const float* g1 = dec_ln + ((size_t)(l * 3 + 1) * 2 + 0) * 512;
    gemmln_k<0, 3><<<dim3(32, 8), 256, 0, stream>>>(
        ybuf, dec_attn_wt + (size_t)(l * 8 + 4) * 262144, g1, g1 + 512,
        dec_attn_b + (size_t)(l * 8 + 4) * 512, cqb, nullptr, 512);
    attn_k<false><<<dim3(32, 16), 128, 0, stream>>>(cqb, 512, 0, ckvb, 2048, l * 512,
                                                    vtc + ((size_t)l << 20), aob);
    gemm_k<64, 32, 2, 0><<<dim3(32, 16), 256, 0, stream>>>(
        aob, dec_attn_wt + (size_t)(l * 8 + 7) * 262144,
        dec_attn_b + (size_t)(l * 8 + 7) * 512, ybuf, ybuf, nullptr, 2048, 512, 512);
    const float* g2 = dec_ln + ((size_t)(l * 3 + 2) * 2 + 0) * 512;
    gemmln_k<1, 0><<<dim3(32, 32), 256, 0, stream>>>(
        ybuf, d_ffn1_wt + (size_t)l * 2048 * 512, g2, g2 + 512,
        dec_ffn_b1 + (size_t)l * 2048, hbuf, nullptr, 2048);
    gemm_k<64, 32, 2, 0><<<dim3(32, 16), 256, 0, stream>>>(
        hbuf, d_ffn2_wt + (size_t)l * 512 * 2048,
        dec_ffn_b2 + (size_t)l * 512, ybuf, ybuf, nullptr, 2048, 512, 2048);
  }

  // ---- final LN + logits (XCD swizzle + NT stores)
  ln_k<<<512, 256, 0, stream>>>(ybuf, dec_fln, dec_fln + 512, nbuf);
  gemm_k<128, 64, 3, 0, true, true><<<dim3(16, 500), 256, 0, stream>>>(
      nbuf, out_wt, out_b, nullptr, logits, nullptr, 2048, VOC, 512);
}

// Round 9
// 966.066 us; speedup vs baseline: 1.9138x; 1.9138x over previous
//
#include <hip/hip_runtime.h>
#include <cstdint>
#include <cstddef>

#define S_LEN 1024
#define DM 512
#define NHEAD 8
#define HDIM 64
#define NLAYER 4
#define FFD 2048
#define VOC 32000
#define WINSZ 128
#define GLOBSZ 16

using half8 = __attribute__((ext_vector_type(8))) _Float16;
using f32x4 = __attribute__((ext_vector_type(4))) float;

static __device__ __forceinline__ f32x4 mfma16(half8 a, half8 b, f32x4 c) {
  return __builtin_amdgcn_mfma_f32_16x16x32_f16(a, b, c, 0, 0, 0);
}

typedef __attribute__((address_space(1))) const void gvoid;
typedef __attribute__((address_space(3))) void lvoid;
static __device__ __forceinline__ void gload16(const void* g, void* l) {
  __builtin_amdgcn_global_load_lds((gvoid*)g, (lvoid*)l, 16, 0, 0);
}
template <int N>
static __device__ __forceinline__ void waitv() {
  asm volatile("s_waitcnt vmcnt(%0)" :: "i"(N) : "memory");
}

// ---------- batched transpose + cast: picks (inA,outA) for z<splitZ else (inB,outB)
__global__ __launch_bounds__(256) void transpose2_k(const float* __restrict__ inA,
                                                    const float* __restrict__ inB,
                                                    _Float16* __restrict__ outA,
                                                    _Float16* __restrict__ outB,
                                                    int R, int C, int splitZ)
{
  __shared__ float t[32][33];
  int z = blockIdx.z;
  const float* ip;
  _Float16* op;
  if (z < splitZ) { ip = inA + (size_t)z * R * C; op = outA + (size_t)z * R * C; }
  else { ip = inB + (size_t)(z - splitZ) * R * C; op = outB + (size_t)(z - splitZ) * R * C; }
  int c0 = blockIdx.x * 32, r0 = blockIdx.y * 32;
  int tx = threadIdx.x & 31, ty = threadIdx.x >> 5;
#pragma unroll
  for (int i = 0; i < 32; i += 8)
    t[ty + i][tx] = ip[(size_t)(r0 + ty + i) * C + c0 + tx];
  __syncthreads();
#pragma unroll
  for (int i = 0; i < 32; i += 8)
    op[(size_t)(c0 + ty + i) * R + r0 + tx] = (_Float16)t[tx][ty + i];
}

// ---------- fused dual embedding gather * sqrt(D) + LayerNorm
__global__ __launch_bounds__(256) void embed2_k(const int* __restrict__ src,
                                                const int* __restrict__ tgt,
                                                const float* __restrict__ enc_embed,
                                                const float* __restrict__ dec_embed,
                                                const float* __restrict__ enc_ln0,
                                                const float* __restrict__ dec_ln0,
                                                float* __restrict__ xbuf,
                                                float* __restrict__ ybuf,
                                                _Float16* __restrict__ nbuf,
                                                _Float16* __restrict__ nbuf2)
{
  int which = blockIdx.y;
  const int* ids = which ? tgt : src;
  const float* emb = which ? dec_embed : enc_embed;
  const float* gamma = which ? dec_ln0 : enc_ln0;
  const float* beta = gamma + 512;
  float* xout = which ? ybuf : xbuf;
  _Float16* nout = which ? nbuf2 : nbuf;

  int row = blockIdx.x * 4 + (threadIdx.x >> 6);
  int lane = threadIdx.x & 63;
  const float* er = emb + (size_t)ids[row] * DM + lane * 8;
  float4 v0 = *(const float4*)er;
  float4 v1 = *(const float4*)(er + 4);
  float vals[8] = {v0.x, v0.y, v0.z, v0.w, v1.x, v1.y, v1.z, v1.w};
  float s = 0.f, ss = 0.f;
#pragma unroll
  for (int j = 0; j < 8; ++j) {
    vals[j] *= 22.627416997969522f;
    s += vals[j]; ss += vals[j] * vals[j];
  }
#pragma unroll
  for (int m = 1; m < 64; m <<= 1) { s += __shfl_xor(s, m); ss += __shfl_xor(ss, m); }
  float mean = s * (1.f / 512.f);
  float var = ss * (1.f / 512.f) - mean * mean;
  float rstd = rsqrtf(var + 1e-5f);
  float* xr = xout + (size_t)row * DM + lane * 8;
  _Float16* orow = nout + (size_t)row * DM + lane * 8;
  const float* gp = gamma + lane * 8;
  const float* bp = beta + lane * 8;
#pragma unroll
  for (int j = 0; j < 8; ++j) {
    xr[j] = vals[j];
    orow[j] = (_Float16)(gp[j] * (vals[j] - mean) * rstd + bp[j]);
  }
}

// ---------- LayerNorm fp32 -> fp16 (one wave per row of 512)
__global__ __launch_bounds__(256) void ln_k(const float* __restrict__ x,
                                            const float* __restrict__ gamma,
                                            const float* __restrict__ beta,
                                            _Float16* __restrict__ outp)
{
  int row = blockIdx.x * 4 + (threadIdx.x >> 6);
  int lane = threadIdx.x & 63;
  const float* xr = x + (size_t)row * DM + lane * 8;
  float4 v0 = *(const float4*)xr;
  float4 v1 = *(const float4*)(xr + 4);
  float vals[8] = {v0.x, v0.y, v0.z, v0.w, v1.x, v1.y, v1.z, v1.w};
  float s = 0.f, ss = 0.f;
#pragma unroll
  for (int j = 0; j < 8; ++j) { s += vals[j]; ss += vals[j] * vals[j]; }
#pragma unroll
  for (int m = 1; m < 64; m <<= 1) { s += __shfl_xor(s, m); ss += __shfl_xor(ss, m); }
  float mean = s * (1.f / 512.f);
  float var = ss * (1.f / 512.f) - mean * mean;
  float rstd = rsqrtf(var + 1e-5f);
  _Float16* orow = outp + (size_t)row * DM + lane * 8;
  const float* gp = gamma + lane * 8;
  const float* bp = beta + lane * 8;
#pragma unroll
  for (int j = 0; j < 8; ++j)
    orow[j] = (_Float16)(gp[j] * (vals[j] - mean) * rstd + bp[j]);
}

// ---------- GEMM: C[M,N] = A[M,K](f16) * B^T[N,K](f16) + bias
// EPI: 0 bias->f16 ; 1 bias+gelu->f16 ; 2 bias+residual->f32 ; 3 bias->f32
// MODE: 0 plain
//       1 self-QKV (N=1536): rope+scale Q (col<512), rope K ([512,1024)), V -> V^T
//       2 batched cross-KV (N=4096, B/bias remapped from dec blocks): rope K, V -> V^T
//       3 rope+scale all cols (cross-Q, N=512)
// SWZ: bijective XCD-aware block swizzle. NT: nontemporal f32 stores.
// Round-4/7 structure: WIDE=(BN>=64), 3-buffer counted vmcnt, compute-then-stage.
template <int BM, int BN, int EPI, int MODE, bool SWZ = false, bool NT = false>
__global__ __launch_bounds__(256) void gemm_k(const _Float16* __restrict__ A,
                                              const _Float16* __restrict__ B,
                                              const float* __restrict__ bias,
                                              const float* __restrict__ resid,
                                              void* __restrict__ Cout,
                                              _Float16* __restrict__ vtout,
                                              int M, int N, int K)
{
  constexpr bool WIDE = (BN >= 64);
  constexpr int WAVE_M = WIDE ? BM / 4 : BM / 2;
  constexpr int WAVE_N = WIDE ? BN : BN / 2;
  constexpr int FMW = WAVE_M / 16;
  constexpr int FNW = WIDE ? BN / 16 : BN / 32;
  constexpr int LPS = BM / 32 + BN / 32;
  static_assert(MODE == 0 || (WIDE && BN == 64), "rope modes need 64-col waves");

  __shared__ __align__(16) _Float16 As[3][BM * 64];
  __shared__ __align__(16) _Float16 Bs[3][BN * 64];
  const int tid = threadIdx.x;
  const int lane = tid & 63, wid = tid >> 6;
  const int g = lane >> 4, ql = lane & 15;

  int bm, bn;
  if constexpr (SWZ) {
    const int gx = gridDim.x;
    const int nwg = gx * gridDim.y;
    const int orig = blockIdx.y * gx + blockIdx.x;
    const int q = nwg >> 3, r = nwg & 7;
    const int xcd = orig & 7, rest = orig >> 3;
    const int id = (xcd < r ? xcd * (q + 1) : r * (q + 1) + (xcd - r) * q) + rest;
    bm = (id % gx) * BM; bn = (id / gx) * BN;
  } else {
    bm = blockIdx.x * BM; bn = blockIdx.y * BN;
  }
  const int wm = WIDE ? wid * WAVE_M : (wid >> 1) * WAVE_M;
  const int wn = WIDE ? 0 : (wid & 1) * WAVE_N;

  const _Float16* Bp;
  if constexpr (MODE == 2) {
    int srcrow0 = ((bn >> 10) * 8 + 5 + ((bn >> 9) & 1)) * 512 + (bn & 511);
    Bp = B + (size_t)srcrow0 * K;
  } else {
    Bp = B + (size_t)bn * K;
  }

  f32x4 acc[FMW][FNW];
#pragma unroll
  for (int a = 0; a < FMW; ++a)
#pragma unroll
    for (int b = 0; b < FNW; ++b) acc[a][b] = f32x4{0.f, 0.f, 0.f, 0.f};

  auto stage = [&](int buf, int kt) {
#pragma unroll
    for (int r2 = 0; r2 < BM / 32; ++r2) {
      int off = r2 * 4096 + tid * 16;
      int row = off >> 7, slot = (off >> 4) & 7;
      gload16(A + (size_t)(bm + row) * K + kt + ((slot ^ (row & 7)) << 3),
              (char*)&As[buf][0] + r2 * 4096 + wid * 1024);
    }
#pragma unroll
    for (int r2 = 0; r2 < BN / 32; ++r2) {
      int off = r2 * 4096 + tid * 16;
      int row = off >> 7, slot = (off >> 4) & 7;
      gload16(Bp + (size_t)row * K + kt + ((slot ^ (row & 7)) << 3),
              (char*)&Bs[buf][0] + r2 * 4096 + wid * 1024);
    }
  };

  auto compute = [&](int cur) {
#pragma unroll
    for (int kk = 0; kk < 2; ++kk) {
      half8 af[FMW], bf[FNW];
#pragma unroll
      for (int a = 0; a < FMW; ++a) {
        int row = wm + a * 16 + ql;
        af[a] = *(const half8*)((const char*)&As[cur][0] + row * 128 + (((kk * 4 + g) ^ (row & 7)) << 4));
      }
#pragma unroll
      for (int b = 0; b < FNW; ++b) {
        int row = wn + b * 16 + ql;
        bf[b] = *(const half8*)((const char*)&Bs[cur][0] + row * 128 + (((kk * 4 + g) ^ (row & 7)) << 4));
      }
#pragma unroll
      for (int a = 0; a < FMW; ++a)
#pragma unroll
        for (int b = 0; b < FNW; ++b) acc[a][b] = mfma16(af[a], bf[b], acc[a][b]);
    }
  };

  const int nk = K >> 6;
  stage(0, 0);
  stage(1, 64);
  for (int t = 0; t < nk; ++t) {
    if (t + 1 < nk) waitv<LPS>(); else waitv<0>();
    __builtin_amdgcn_s_barrier();
    __builtin_amdgcn_sched_barrier(0);
    compute(t % 3);
    if (t + 2 < nk) stage((t + 2) % 3, (t + 2) << 6);
  }

#pragma unroll
  for (int a = 0; a < FMW; ++a) {
    const int row0 = bm + wm + a * 16 + g * 4;
    float v[FNW][4];
#pragma unroll
    for (int b2 = 0; b2 < FNW; ++b2) {
      int col = bn + wn + b2 * 16 + ql;
      float bv;
      if constexpr (MODE == 2) {
        int bcol = ((col >> 10) * 8 + 5 + ((col >> 9) & 1)) * 512 + (col & 511);
        bv = bias[bcol];
      } else {
        bv = bias[col];
      }
#pragma unroll
      for (int r2 = 0; r2 < 4; ++r2) v[b2][r2] = acc[a][b2][r2] + bv;
    }
    if constexpr (MODE != 0) {
      const int seg = bn >> 9;
      bool dorope = (MODE == 3) || (MODE == 1 && seg < 2) ||
                    (MODE == 2 && ((bn >> 9) & 1) == 0);
      if (dorope) {
        const float scale = (MODE == 3 || (MODE == 1 && seg == 0)) ? 0.125f : 1.0f;
#pragma unroll
        for (int b2 = 0; b2 < 2; ++b2) {
          int d = b2 * 16 + ql;
          float inv = __expf(-(float)d * 0.28782313662425574f); // 10000^(-d/32)
#pragma unroll
          for (int r2 = 0; r2 < 4; ++r2) {
            float sp = (float)((row0 & 1023) + r2);
            float sn, cs; __sincosf(sp * inv, &sn, &cs);
            float x1 = v[b2][r2], x2 = v[b2 + 2][r2];
            v[b2][r2]     = (x1 * cs - x2 * sn) * scale;
            v[b2 + 2][r2] = (x1 * sn + x2 * cs) * scale;
          }
        }
      }
    }
#pragma unroll
    for (int b2 = 0; b2 < FNW; ++b2) {
      int col = bn + wn + b2 * 16 + ql;
      if constexpr (MODE == 1) {
        if (col < 1024) {
#pragma unroll
          for (int r2 = 0; r2 < 4; ++r2)
            ((_Float16*)Cout)[(size_t)(row0 + r2) * 1024 + col] = (_Float16)v[b2][r2];
        } else {
          int rowidx = ((row0 >> 10) << 9) + (col - 1024);
          union { _Float16 h[4]; uint2 u; } pk;
#pragma unroll
          for (int r2 = 0; r2 < 4; ++r2) pk.h[r2] = (_Float16)v[b2][r2];
          *(uint2*)&vtout[((size_t)rowidx << 10) + (row0 & 1023)] = pk.u;
        }
      } else if constexpr (MODE == 2) {
        if ((col & 1023) < 512) {
#pragma unroll
          for (int r2 = 0; r2 < 4; ++r2)
            ((_Float16*)Cout)[(size_t)(row0 + r2) * 2048 + ((col >> 10) << 9) + (col & 511)] = (_Float16)v[b2][r2];
        } else {
          int rowidx = (col & ~1023) + ((row0 >> 10) << 9) + (col & 511);
          union { _Float16 h[4]; uint2 u; } pk;
#pragma unroll
          for (int r2 = 0; r2 < 4; ++r2) pk.h[r2] = (_Float16)v[b2][r2];
          *(uint2*)&vtout[((size_t)rowidx << 10) + (row0 & 1023)] = pk.u;
        }
      } else {
#pragma unroll
        for (int r2 = 0; r2 < 4; ++r2) {
          float x = v[b2][r2];
          if constexpr (EPI == 1) {
            float u = x;
            x = u / (1.f + __expf(-1.5957691216057308f * (u + 0.044715f * u * u * u)));
          }
          if constexpr (EPI == 2) x += resid[(size_t)(row0 + r2) * N + col];
          if constexpr (EPI == 0 || EPI == 1)
            ((_Float16*)Cout)[(size_t)(row0 + r2) * N + col] = (_Float16)x;
          else if constexpr (NT)
            __builtin_nontemporal_store(x, &((float*)Cout)[(size_t)(row0 + r2) * N + col]);
          else
            ((float*)Cout)[(size_t)(row0 + r2) * N + col] = x;
        }
      }
    }
  }
}

// ---------- dedicated logits GEMM: BM=128, BN=64, 2-buffer classic 2-phase,
// 48KB LDS -> 3 blocks/CU, XCD swizzle + NT f32 stores.
__global__ __launch_bounds__(256) void gemmlg_k(const _Float16* __restrict__ A,
                                                const _Float16* __restrict__ B,
                                                const float* __restrict__ bias,
                                                float* __restrict__ Cout,
                                                int N, int K)
{
  __shared__ __align__(16) _Float16 As[2][128 * 64];
  __shared__ __align__(16) _Float16 Bs[2][64 * 64];
  const int tid = threadIdx.x;
  const int lane = tid & 63, wid = tid >> 6;
  const int g = lane >> 4, ql = lane & 15;

  const int gx = gridDim.x;
  const int nwg = gx * gridDim.y;
  const int orig = blockIdx.y * gx + blockIdx.x;
  const int q = nwg >> 3, r = nwg & 7;
  const int xcd = orig & 7, rest = orig >> 3;
  const int id = (xcd < r ? xcd * (q + 1) : r * (q + 1) + (xcd - r) * q) + rest;
  const int bm = (id % gx) * 128, bn = (id / gx) * 64;
  const int wm = wid * 32;

  const _Float16* Bp = B + (size_t)bn * K;

  f32x4 acc[2][4];
#pragma unroll
  for (int a = 0; a < 2; ++a)
#pragma unroll
    for (int b = 0; b < 4; ++b) acc[a][b] = f32x4{0.f, 0.f, 0.f, 0.f};

  auto stage = [&](int buf, int kt) {
#pragma unroll
    for (int r2 = 0; r2 < 4; ++r2) {
      int off = r2 * 4096 + tid * 16;
      int row = off >> 7, slot = (off >> 4) & 7;
      gload16(A + (size_t)(bm + row) * K + kt + ((slot ^ (row & 7)) << 3),
              (char*)&As[buf][0] + r2 * 4096 + wid * 1024);
    }
#pragma unroll
    for (int r2 = 0; r2 < 2; ++r2) {
      int off = r2 * 4096 + tid * 16;
      int row = off >> 7, slot = (off >> 4) & 7;
      gload16(Bp + (size_t)row * K + kt + ((slot ^ (row & 7)) << 3),
              (char*)&Bs[buf][0] + r2 * 4096 + wid * 1024);
    }
  };

  const int nk = K >> 6;
  stage(0, 0);
  for (int t = 0; t < nk; ++t) {
    waitv<0>();
    __builtin_amdgcn_s_barrier();   // buf t ready; previous compute done
    __builtin_amdgcn_sched_barrier(0);
    if (t + 1 < nk) stage((t + 1) & 1, (t + 1) << 6);  // flies under compute(t)
    const int cur = t & 1;
#pragma unroll
    for (int kk = 0; kk < 2; ++kk) {
      half8 af[2], bf[4];
#pragma unroll
      for (int a = 0; a < 2; ++a) {
        int row = wm + a * 16 + ql;
        af[a] = *(const half8*)((const char*)&As[cur][0] + row * 128 + (((kk * 4 + g) ^ (row & 7)) << 4));
      }
#pragma unroll
      for (int b = 0; b < 4; ++b) {
        int row = b * 16 + ql;
        bf[b] = *(const half8*)((const char*)&Bs[cur][0] + row * 128 + (((kk * 4 + g) ^ (row & 7)) << 4));
      }
#pragma unroll
      for (int a = 0; a < 2; ++a)
#pragma unroll
        for (int b = 0; b < 4; ++b) acc[a][b] = mfma16(af[a], bf[b], acc[a][b]);
    }
  }

#pragma unroll
  for (int a = 0; a < 2; ++a) {
    const int row0 = bm + wm + a * 16 + g * 4;
#pragma unroll
    for (int b2 = 0; b2 < 4; ++b2) {
      int col = bn + b2 * 16 + ql;
      float bv = bias[col];
#pragma unroll
      for (int r2 = 0; r2 < 4; ++r2)
        __builtin_nontemporal_store(acc[a][b2][r2] + bv,
                                    &Cout[(size_t)(row0 + r2) * N + col]);
    }
  }
}

// ---------- banded flash attention; Q/K pre-roped (Q pre-scaled), V in V^T layout
// 2 waves/block (32 q-rows) -> 512 blocks = 2 blocks/CU.
template <bool CAUSAL>
__global__ __launch_bounds__(128) void attn_k(const _Float16* __restrict__ qb, int qs, int qoff,
                                              const _Float16* __restrict__ kb, int ks, int koff,
                                              const _Float16* __restrict__ vt,
                                              _Float16* __restrict__ out)
{
  __shared__ _Float16 plds[2][16 * 40];
  const int bh = blockIdx.y, b = bh >> 3, h = bh & 7;
  const int wid = threadIdx.x >> 6, lane = threadIdx.x & 63;
  const int g = lane >> 4, ql = lane & 15;
  const int q0 = blockIdx.x * 32 + wid * 16;
  const size_t rb = (size_t)b * S_LEN;

  half8 qf0, qf1;
  {
    const _Float16* qp = qb + (rb + q0 + ql) * qs + qoff + h * HDIM + g * 8;
    qf0 = *(const half8*)qp;
    qf1 = *(const half8*)(qp + 32);
  }
  float mrun[4] = {-1e30f, -1e30f, -1e30f, -1e30f};
  float srun[4] = {0.f, 0.f, 0.f, 0.f};
  f32x4 oacc[4];
#pragma unroll
  for (int c = 0; c < 4; ++c) oacc[c] = f32x4{0.f, 0.f, 0.f, 0.f};

  const _Float16* vbase = vt + (((size_t)(b * 512 + h * HDIM)) << 10);
  _Float16* pw = plds[wid];

  auto proc = [&](int k0) {
    const _Float16* kp = kb + (rb + k0 + ql) * ks + koff + h * HDIM + g * 8;
    half8 kf00 = *(const half8*)kp;
    half8 kf01 = *(const half8*)(kp + 32);
    half8 kf10 = *(const half8*)(kp + (size_t)16 * ks);
    half8 kf11 = *(const half8*)(kp + (size_t)16 * ks + 32);

    f32x4 s0 = f32x4{0.f, 0.f, 0.f, 0.f};
    f32x4 s1 = f32x4{0.f, 0.f, 0.f, 0.f};
    s0 = mfma16(qf0, kf00, s0); s0 = mfma16(qf1, kf01, s0);
    s1 = mfma16(qf0, kf10, s1); s1 = mfma16(qf1, kf11, s1);

    float p0[4], p1[4];
#pragma unroll
    for (int r = 0; r < 4; ++r) {
      int i = q0 + 4 * g + r;
      int j0 = k0 + ql, j1 = j0 + 16;
      float a0 = s0[r], a1 = s1[r];
      int d0 = i - j0, d1 = i - j1;
      bool ok0 = (d0 <= WINSZ && d0 >= -WINSZ) || (i < GLOBSZ) || (j0 < GLOBSZ);
      bool ok1 = (d1 <= WINSZ && d1 >= -WINSZ) || (i < GLOBSZ) || (j1 < GLOBSZ);
      if (CAUSAL) { ok0 = ok0 && (j0 <= i); ok1 = ok1 && (j1 <= i); }
      a0 = ok0 ? a0 : -1e9f;
      a1 = ok1 ? a1 : -1e9f;
      float mx = fmaxf(a0, a1);
      mx = fmaxf(mx, __shfl_xor(mx, 1));
      mx = fmaxf(mx, __shfl_xor(mx, 2));
      mx = fmaxf(mx, __shfl_xor(mx, 4));
      mx = fmaxf(mx, __shfl_xor(mx, 8));
      float mnew = fmaxf(mrun[r], mx);
      float alpha = __expf(mrun[r] - mnew);
      float e0 = __expf(a0 - mnew), e1 = __expf(a1 - mnew);
      float ps = e0 + e1;
      ps += __shfl_xor(ps, 1);
      ps += __shfl_xor(ps, 2);
      ps += __shfl_xor(ps, 4);
      ps += __shfl_xor(ps, 8);
      srun[r] = srun[r] * alpha + ps;
      mrun[r] = mnew;
#pragma unroll
      for (int c = 0; c < 4; ++c) oacc[c][r] *= alpha;
      p0[r] = e0; p1[r] = e1;
    }
#pragma unroll
    for (int r = 0; r < 4; ++r) {
      pw[(4 * g + r) * 40 + ql] = (_Float16)p0[r];
      pw[(4 * g + r) * 40 + 16 + ql] = (_Float16)p1[r];
    }
    half8 pa = *(const half8*)&pw[ql * 40 + g * 8];
#pragma unroll
    for (int c = 0; c < 4; ++c) {
      half8 vf = *(const half8*)(vbase + (((size_t)(16 * c + ql)) << 10) + k0 + 8 * g);
      oacc[c] = mfma16(pa, vf, oacc[c]);
    }
  };

  const int kend = CAUSAL ? (q0 + 16) : S_LEN;
  int lo = 0, hi = kend;
  if (q0 >= GLOBSZ) {
    lo = (q0 - WINSZ) & ~31;
    if (lo < 0) lo = 0;
    if (!CAUSAL) {
      int h2 = q0 + 16 + WINSZ;
      hi = (h2 < kend) ? h2 : kend;
    }
  }
  if (lo > 0) proc(0);
  for (int k0 = lo; k0 < hi; k0 += 32) proc(k0);

#pragma unroll
  for (int c = 0; c < 4; ++c)
#pragma unroll
    for (int r = 0; r < 4; ++r) {
      float val = oacc[c][r] / srun[r];
      out[(rb + q0 + 4 * g + r) * DM + h * HDIM + 16 * c + ql] = (_Float16)val;
    }
}

// =====================================================================
extern "C" void kernel_launch(void* const* d_in, const int* in_sizes, int n_in,
                              void* d_out, int out_size, void* d_ws, size_t ws_size,
                              hipStream_t stream)
{
  const int*   src         = (const int*)d_in[0];
  const int*   tgt         = (const int*)d_in[1];
  const float* enc_embed   = (const float*)d_in[2];
  const float* dec_embed   = (const float*)d_in[3];
  const float* enc_attn_w  = (const float*)d_in[4];
  const float* enc_attn_b  = (const float*)d_in[5];
  const float* enc_ln      = (const float*)d_in[6];
  const float* enc_ffn_w1  = (const float*)d_in[7];
  const float* enc_ffn_b1  = (const float*)d_in[8];
  const float* enc_ffn_w2  = (const float*)d_in[9];
  const float* enc_ffn_b2  = (const float*)d_in[10];
  const float* enc_fln     = (const float*)d_in[11];
  const float* dec_attn_w  = (const float*)d_in[12];
  const float* dec_attn_b  = (const float*)d_in[13];
  const float* dec_ln      = (const float*)d_in[14];
  const float* dec_ffn_w1  = (const float*)d_in[15];
  const float* dec_ffn_b1  = (const float*)d_in[16];
  const float* dec_ffn_w2  = (const float*)d_in[17];
  const float* dec_ffn_b2  = (const float*)d_in[18];
  const float* dec_fln     = (const float*)d_in[19];
  const float* out_w       = (const float*)d_in[20];
  const float* out_b       = (const float*)d_in[21];
  float* logits = (float*)d_out;

  char* wsp = (char*)d_ws;
  size_t off = 0;
  auto alloc = [&](size_t bytes) -> void* {
    void* p = wsp + off;
    off += (bytes + 255) & ~(size_t)255;
    return p;
  };
  _Float16* enc_attn_wt = (_Float16*)alloc((size_t)16 * 512 * 512 * 2);
  _Float16* dec_attn_wt = (_Float16*)alloc((size_t)32 * 512 * 512 * 2);
  _Float16* e_ffn1_wt   = (_Float16*)alloc((size_t)4 * 2048 * 512 * 2);
  _Float16* e_ffn2_wt   = (_Float16*)alloc((size_t)4 * 2048 * 512 * 2);
  _Float16* d_ffn1_wt   = (_Float16*)alloc((size_t)4 * 2048 * 512 * 2);
  _Float16* d_ffn2_wt   = (_Float16*)alloc((size_t)4 * 2048 * 512 * 2);
  _Float16* out_wt      = (_Float16*)alloc((size_t)VOC * 512 * 2);
  float*    xbuf        = (float*)alloc((size_t)2048 * 512 * 4);
  float*    ybuf        = (float*)alloc((size_t)2048 * 512 * 4);
  _Float16* nbuf        = (_Float16*)alloc((size_t)2048 * 512 * 2);
  _Float16* nbuf2       = (_Float16*)alloc((size_t)2048 * 512 * 2);
  _Float16* qkvb        = (_Float16*)alloc((size_t)2048 * 1024 * 2);
  _Float16* aob         = (_Float16*)alloc((size_t)2048 * 512 * 2);
  _Float16* hbuf        = (_Float16*)alloc((size_t)2048 * 2048 * 2);
  _Float16* memb        = (_Float16*)alloc((size_t)2048 * 512 * 2);
  _Float16* cqb         = (_Float16*)alloc((size_t)2048 * 512 * 2);
  _Float16* ckvb        = (_Float16*)alloc((size_t)2048 * 2048 * 2);
  _Float16* vts         = (_Float16*)alloc((size_t)2 * 512 * 1024 * 2);
  _Float16* vtc         = (_Float16*)alloc((size_t)8 * 512 * 1024 * 2);

  // ---- weight prep (transpose + fp16 cast), batched
  transpose2_k<<<dim3(16, 16, 48), 256, 0, stream>>>(enc_attn_w, dec_attn_w,
                                                     enc_attn_wt, dec_attn_wt, 512, 512, 16);
  transpose2_k<<<dim3(64, 16, 8), 256, 0, stream>>>(enc_ffn_w1, dec_ffn_w1,
                                                    e_ffn1_wt, d_ffn1_wt, 512, 2048, 4);
  transpose2_k<<<dim3(16, 64, 8), 256, 0, stream>>>(enc_ffn_w2, dec_ffn_w2,
                                                    e_ffn2_wt, d_ffn2_wt, 2048, 512, 4);
  transpose2_k<<<dim3(1000, 16, 1), 256, 0, stream>>>(out_w, out_w, out_wt, out_wt, 512, VOC, 1);

  embed2_k<<<dim3(512, 2), 256, 0, stream>>>(src, tgt, enc_embed, dec_embed,
                                             enc_ln, dec_ln, xbuf, ybuf, nbuf, nbuf2);

  // ---- encoder
  for (int l = 0; l < NLAYER; ++l) {
    const float* g0 = enc_ln + ((size_t)(l * 2 + 0) * 2 + 0) * 512;
    if (l > 0) ln_k<<<512, 256, 0, stream>>>(xbuf, g0, g0 + 512, nbuf);
    gemm_k<64, 64, 0, 1, true><<<dim3(32, 24), 256, 0, stream>>>(
        nbuf, enc_attn_wt + (size_t)l * 4 * 262144,
        enc_attn_b + (size_t)l * 4 * 512, nullptr, qkvb, vts, 2048, 1536, 512);
    attn_k<false><<<dim3(32, 16), 128, 0, stream>>>(qkvb, 1024, 0, qkvb, 1024, 512, vts, aob);
    gemm_k<64, 32, 2, 0><<<dim3(32, 16), 256, 0, stream>>>(
        aob, enc_attn_wt + (size_t)(l * 4 + 3) * 262144,
        enc_attn_b + (size_t)(l * 4 + 3) * 512, xbuf, xbuf, nullptr, 2048, 512, 512);
    const float* g1 = enc_ln + ((size_t)(l * 2 + 1) * 2 + 0) * 512;
    ln_k<<<512, 256, 0, stream>>>(xbuf, g1, g1 + 512, nbuf);
    gemm_k<64, 64, 1, 0, true><<<dim3(32, 32), 256, 0, stream>>>(
        nbuf, e_ffn1_wt + (size_t)l * 2048 * 512,
        enc_ffn_b1 + (size_t)l * 2048, nullptr, hbuf, nullptr, 2048, 2048, 512);
    gemm_k<64, 32, 2, 0><<<dim3(32, 16), 256, 0, stream>>>(
        hbuf, e_ffn2_wt + (size_t)l * 512 * 2048,
        enc_ffn_b2 + (size_t)l * 512, xbuf, xbuf, nullptr, 2048, 512, 2048);
  }
  ln_k<<<512, 256, 0, stream>>>(xbuf, enc_fln, enc_fln + 512, memb);

  // ---- all 4 decoder layers' cross K/V projections in one GEMM (weights remapped in-kernel)
  gemm_k<64, 64, 0, 2, true><<<dim3(32, 64), 256, 0, stream>>>(
      memb, dec_attn_wt, dec_attn_b, nullptr, ckvb, vtc, 2048, 4096, 512);

  // ---- decoder
  for (int l = 0; l < NLAYER; ++l) {
    const float* g0 = dec_ln + ((size_t)(l * 3 + 0) * 2 + 0) * 512;
    const _Float16* dn = (l == 0) ? nbuf2 : nbuf;
    if (l > 0) ln_k<<<512, 256, 0, stream>>>(ybuf, g0, g0 + 512, nbuf);
    gemm_k<64, 64, 0, 1, true><<<dim3(32, 24), 256, 0, stream>>>(
        dn, dec_attn_wt + (size_t)l * 8 * 262144,
        dec_attn_b + (size_t)l * 8 * 512, nullptr, qkvb, vts, 2048, 1536, 512);
    attn_k<true><<<dim3(32, 16), 128, 0, stream>>>(qkvb, 1024, 0, qkvb, 1024, 512, vts, aob);
    gemm_k<64, 32, 2, 0><<<dim3(32, 16), 256, 0, stream>>>(
        aob, dec_attn_wt + (size_t)(l * 8 + 3) * 262144,
        dec_attn_b + (size_t)(l * 8 + 3) * 512, ybuf, ybuf, nullptr, 2048, 512, 512);
    const float* g1 = dec_ln + ((size_t)(l * 3 + 1) * 2 + 0) * 512;
    ln_k<<<512, 256, 0, stream>>>(ybuf, g1, g1 + 512, nbuf);
    gemm_k<64, 64, 0, 3><<<dim3(32, 8), 256, 0, stream>>>(
        nbuf, dec_attn_wt + (size_t)(l * 8 + 4) * 262144,
        dec_attn_b + (size_t)(l * 8 + 4) * 512, nullptr, cqb, nullptr, 2048, 512, 512);
    attn_k<false><<<dim3(32, 16), 128, 0, stream>>>(cqb, 512, 0, ckvb, 2048, l * 512,
                                                    vtc + ((size_t)l << 20), aob);
    gemm_k<64, 32, 2, 0><<<dim3(32, 16), 256, 0, stream>>>(
        aob, dec_attn_wt + (size_t)(l * 8 + 7) * 262144,
        dec_attn_b + (size_t)(l * 8 + 7) * 512, ybuf, ybuf, nullptr, 2048, 512, 512);
    const float* g2 = dec_ln + ((size_t)(l * 3 + 2) * 2 + 0) * 512;
    ln_k<<<512, 256, 0, stream>>>(ybuf, g2, g2 + 512, nbuf);
    gemm_k<64, 64, 1, 0, true><<<dim3(32, 32), 256, 0, stream>>>(
        nbuf, d_ffn1_wt + (size_t)l * 2048 * 512,
        dec_ffn_b1 + (size_t)l * 2048, nullptr, hbuf, nullptr, 2048, 2048, 512);
    gemm_k<64, 32, 2, 0><<<dim3(32, 16), 256, 0, stream>>>(
        hbuf, d_ffn2_wt + (size_t)l * 512 * 2048,
        dec_ffn_b2 + (size_t)l * 512, ybuf, ybuf, nullptr, 2048, 512, 2048);
  }

  // ---- final LN + logits (2-buffer 3-blocks/CU kernel, XCD swizzle + NT stores)
  ln_k<<<512, 256, 0, stream>>>(ybuf, dec_fln, dec_fln + 512, nbuf);
  gemmlg_k<<<dim3(16, 500), 256, 0, stream>>>(nbuf, out_wt, out_b, logits, VOC, 512);
}